// Round 1
// baseline (675.942 us; speedup 1.0000x reference)
//
#include <hip/hip_runtime.h>
#include <hip/hip_bf16.h>

typedef __attribute__((ext_vector_type(8))) short s16x8;
typedef __attribute__((ext_vector_type(4))) float f32x4;

#define TOK 131072   // 8*128*128 tokens
#define CD 192
#define HIDD 768

__device__ __forceinline__ unsigned short f2bf(float f){
    __hip_bfloat16 h = __float2bfloat16(f);
    return *reinterpret_cast<unsigned short*>(&h);
}

__device__ __forceinline__ int flab(int g){ return (g < 120) ? 0 : ((g < 124) ? 1 : 2); }

// ---------------- weight fp32 -> bf16 ----------------
__global__ __launch_bounds__(256) void wconv_all(
    const float* __restrict__ w0, const float* __restrict__ w1,
    const float* __restrict__ w2, const float* __restrict__ w3,
    unsigned short* __restrict__ o0, unsigned short* __restrict__ o1,
    unsigned short* __restrict__ o2, unsigned short* __restrict__ o3)
{
    int i = blockIdx.x*256 + threadIdx.x;
    if (i < 110592) o0[i] = f2bf(w0[i]);   // qkv_w 576x192
    if (i < 36864)  o1[i] = f2bf(w1[i]);   // proj_w 192x192
    if (i < 147456) o2[i] = f2bf(w2[i]);   // fc1_w 768x192
    if (i < 147456) o3[i] = f2bf(w3[i]);   // fc2_w 192x768
}

// ---------------- LN1 + shift + window partition -> bf16 ----------------
// one wave per destination window-token; writes win[B_*64+n][192] bf16
__global__ __launch_bounds__(256) void ln1_win_kernel(
    const float* __restrict__ x, const float* __restrict__ g,
    const float* __restrict__ b, unsigned short* __restrict__ win)
{
    int wid  = blockIdx.x*4 + (threadIdx.x >> 6);
    int lane = threadIdx.x & 63;
    int b_ = wid >> 6, n = wid & 63;
    int bb = b_ >> 8, wi = b_ & 255;
    int wh = wi >> 4, ww = wi & 15;
    int r = n >> 3, c = n & 7;
    int h = (wh*8 + r + 4) & 127;   // roll(-4): src = dst+4 mod 128
    int w = (ww*8 + c + 4) & 127;
    const float* px = x + (((size_t)bb*128 + h)*128 + w)*192;
    float v0 = px[lane], v1 = px[lane+64], v2 = px[lane+128];
    float s = v0 + v1 + v2;
    #pragma unroll
    for (int o = 1; o < 64; o <<= 1) s += __shfl_xor(s, o);
    float mu = s * (1.0f/192.0f);
    float d0 = v0-mu, d1 = v1-mu, d2 = v2-mu;
    float qv = d0*d0 + d1*d1 + d2*d2;
    #pragma unroll
    for (int o = 1; o < 64; o <<= 1) qv += __shfl_xor(qv, o);
    float rstd = rsqrtf(qv * (1.0f/192.0f) + 1e-5f);
    unsigned short* pw = win + (size_t)wid*192;
    pw[lane]     = f2bf(d0*rstd*g[lane]     + b[lane]);
    pw[lane+64]  = f2bf(d1*rstd*g[lane+64]  + b[lane+64]);
    pw[lane+128] = f2bf(d2*rstd*g[lane+128] + b[lane+128]);
}

// ---------------- LN2 (plain order) ----------------
__global__ __launch_bounds__(256) void ln2_kernel(
    const float* __restrict__ x1, const float* __restrict__ g,
    const float* __restrict__ b, unsigned short* __restrict__ out)
{
    int t = blockIdx.x*4 + (threadIdx.x >> 6);
    int lane = threadIdx.x & 63;
    const float* px = x1 + (size_t)t*192;
    float v0 = px[lane], v1 = px[lane+64], v2 = px[lane+128];
    float s = v0 + v1 + v2;
    #pragma unroll
    for (int o = 1; o < 64; o <<= 1) s += __shfl_xor(s, o);
    float mu = s * (1.0f/192.0f);
    float d0 = v0-mu, d1 = v1-mu, d2 = v2-mu;
    float qv = d0*d0 + d1*d1 + d2*d2;
    #pragma unroll
    for (int o = 1; o < 64; o <<= 1) qv += __shfl_xor(qv, o);
    float rstd = rsqrtf(qv * (1.0f/192.0f) + 1e-5f);
    unsigned short* pw = out + (size_t)t*192;
    pw[lane]     = f2bf(d0*rstd*g[lane]     + b[lane]);
    pw[lane+64]  = f2bf(d1*rstd*g[lane+64]  + b[lane+64]);
    pw[lane+128] = f2bf(d2*rstd*g[lane+128] + b[lane+128]);
}

// ---------------- shared GEMM mainloop: C[64x64] = A[m0..][K] * W[o0..][K]^T ----------------
// block 256 thr = 4 waves; wave w owns rows w*16..w*16+15 x all 64 cols (4 mfma tiles)
// LDS rows padded to 200 bf16 (400B = 100 dwords -> 4r mod 32 banks, 2-way = free)
__device__ __forceinline__ void gemm_mainloop(
    const unsigned short* __restrict__ A, const unsigned short* __restrict__ Wm,
    int K, int m0, int o0, unsigned short* As, unsigned short* Bs, f32x4 acc[4])
{
    const int tid = threadIdx.x;
    const int wave = tid >> 6, lane = tid & 63, lrow = lane & 15, quad = lane >> 4;
    #pragma unroll
    for (int j = 0; j < 4; ++j) acc[j] = (f32x4){0.f,0.f,0.f,0.f};
    for (int k0 = 0; k0 < K; k0 += 192) {
        #pragma unroll
        for (int t = 0; t < 6; ++t) {
            int cid = tid + t*256;              // 0..1535
            int row = cid / 24;
            int col = (cid % 24) * 8;
            *(int4*)(As + row*200 + col) = *(const int4*)(A  + (size_t)(m0+row)*K + (k0+col));
            *(int4*)(Bs + row*200 + col) = *(const int4*)(Wm + (size_t)(o0+row)*K + (k0+col));
        }
        __syncthreads();
        #pragma unroll
        for (int kc = 0; kc < 192; kc += 32) {
            s16x8 af = *(const s16x8*)(As + (wave*16 + lrow)*200 + kc + quad*8);
            #pragma unroll
            for (int j = 0; j < 4; ++j) {
                s16x8 bf = *(const s16x8*)(Bs + (j*16 + lrow)*200 + kc + quad*8);
                acc[j] = __builtin_amdgcn_mfma_f32_16x16x32_bf16(af, bf, acc[j], 0, 0, 0);
            }
        }
        __syncthreads();
    }
}

// ---------------- QKV GEMM: win[131072,192] x qkv_w[576,192]^T ----------------
// q scaled by hd^-0.5; v stored TRANSPOSED [b_,h][d][n] via LDS transpose for coalesced PV frags
__global__ __launch_bounds__(256) void gemm_qkv_kernel(
    const unsigned short* __restrict__ A, const unsigned short* __restrict__ Wm,
    const float* __restrict__ bias, unsigned short* __restrict__ qo,
    unsigned short* __restrict__ ko, unsigned short* __restrict__ vo)
{
    __shared__ __attribute__((aligned(16))) unsigned short As[64*200];
    __shared__ __attribute__((aligned(16))) unsigned short Bs[64*200];
    int m0 = blockIdx.y*64, o0 = blockIdx.x*64;
    f32x4 acc[4];
    gemm_mainloop(A, Wm, 192, m0, o0, As, Bs, acc);
    int tid = threadIdx.x, wave = tid >> 6, lane = tid & 63, lrow = lane & 15, quad = lane >> 4;
    size_t b_ = (size_t)blockIdx.y;          // 64-row tile == one window
    int part = o0 / 192;                     // 0=q 1=k 2=v (64-tiles never straddle)
    if (part < 2) {
        unsigned short* dst = (part == 0) ? qo : ko;
        float scale = (part == 0) ? 0.17677669529663687f : 1.0f;
        #pragma unroll
        for (int j = 0; j < 4; ++j) {
            int o = o0 + j*16 + lrow;
            int rem = o - part*192;
            int head = rem >> 5, d = rem & 31;
            float bv = bias[o];
            #pragma unroll
            for (int rg = 0; rg < 4; ++rg) {
                int n = wave*16 + quad*4 + rg;
                dst[((b_*6 + head)*64 + n)*32 + d] = f2bf((acc[j][rg] + bv) * scale);
            }
        }
    } else {
        // transpose 64x64 tile in LDS (As reuse; mainloop's trailing barrier makes this safe)
        #pragma unroll
        for (int j = 0; j < 4; ++j) {
            int ol = j*16 + lrow;
            float bv = bias[o0 + ol];
            #pragma unroll
            for (int rg = 0; rg < 4; ++rg) {
                int ml = wave*16 + quad*4 + rg;
                As[ol*72 + ml] = f2bf(acc[j][rg] + bv);
            }
        }
        __syncthreads();
        int o = tid >> 2, seg = (tid & 3)*16;
        int rem = o0 + o - 384;
        int head = rem >> 5, d = rem & 31;
        const int4* sp = (const int4*)(As + o*72 + seg);
        int4* dp = (int4*)(vo + ((b_*6 + head)*32 + d)*64 + seg);
        dp[0] = sp[0];
        dp[1] = sp[1];
    }
}

// ---------------- windowed attention: 1 block/window, 6 waves = 6 heads ----------------
__global__ __launch_bounds__(384) void attn_kernel(
    const unsigned short* __restrict__ q, const unsigned short* __restrict__ k,
    const unsigned short* __restrict__ vT, const float* __restrict__ rpb,
    unsigned short* __restrict__ ao)
{
    __shared__ float rpb_s[1350];
    __shared__ __attribute__((aligned(16))) unsigned short p_lds[6*4608];  // per-head 64x72
    const int b_ = blockIdx.x;
    const int h = threadIdx.x >> 6;
    const int lane = threadIdx.x & 63, lrow = lane & 15, quad = lane >> 4;
    for (int i = threadIdx.x; i < 1350; i += 384) rpb_s[i] = rpb[i];
    __syncthreads();

    const size_t hb = ((size_t)b_*6 + h)*2048;
    const unsigned short* qb = q  + hb;   // [n][d]
    const unsigned short* kb = k  + hb;   // [m][d]
    const unsigned short* vb = vT + hb;   // [d][m]

    s16x8 qf[4], kf[4];
    #pragma unroll
    for (int i = 0; i < 4; ++i) qf[i] = *(const s16x8*)(qb + (i*16+lrow)*32 + quad*8);
    #pragma unroll
    for (int j = 0; j < 4; ++j) kf[j] = *(const s16x8*)(kb + (j*16+lrow)*32 + quad*8);

    const f32x4 zz = {0.f,0.f,0.f,0.f};
    f32x4 s[4][4];
    #pragma unroll
    for (int i = 0; i < 4; ++i)
        #pragma unroll
        for (int j = 0; j < 4; ++j)
            s[i][j] = __builtin_amdgcn_mfma_f32_16x16x32_bf16(qf[i], kf[j], zz, 0, 0, 0);

    const int wi = b_ & 255, wh = wi >> 4, ww = wi & 15;
    int labm[4];
    #pragma unroll
    for (int j = 0; j < 4; ++j) {
        int m = j*16 + lrow;
        labm[j] = flab(wh*8 + (m >> 3))*3 + flab(ww*8 + (m & 7));
    }
    unsigned short* pl = p_lds + h*4608;
    #pragma unroll
    for (int i = 0; i < 4; ++i) {
        #pragma unroll
        for (int rg = 0; rg < 4; ++rg) {
            int n = i*16 + quad*4 + rg;
            int rn = n >> 3, cn = n & 7;
            int labn = flab(wh*8 + rn)*3 + flab(ww*8 + cn);
            float vals[4];
            float vmax = -1e30f;
            #pragma unroll
            for (int j = 0; j < 4; ++j) {
                int m = j*16 + lrow;
                int idx = ((rn - (m >> 3) + 7)*15 + (cn - (m & 7) + 7))*6 + h;
                float val = s[i][j][rg] + rpb_s[idx];
                if (labn != labm[j]) val -= 100.f;
                vals[j] = val;
                vmax = fmaxf(vmax, val);
            }
            #pragma unroll
            for (int o = 1; o < 16; o <<= 1) vmax = fmaxf(vmax, __shfl_xor(vmax, o));
            float sum = 0.f;
            #pragma unroll
            for (int j = 0; j < 4; ++j) { vals[j] = __expf(vals[j] - vmax); sum += vals[j]; }
            #pragma unroll
            for (int o = 1; o < 16; o <<= 1) sum += __shfl_xor(sum, o);
            float inv = 1.f / sum;
            #pragma unroll
            for (int j = 0; j < 4; ++j) pl[n*72 + j*16 + lrow] = f2bf(vals[j]*inv);
        }
    }
    __syncthreads();   // P C-layout -> A-layout round trip

    f32x4 oacc[4][2];
    #pragma unroll
    for (int i = 0; i < 4; ++i) { oacc[i][0] = zz; oacc[i][1] = zz; }
    #pragma unroll
    for (int kc = 0; kc < 2; ++kc) {
        s16x8 vf[2];
        #pragma unroll
        for (int jd = 0; jd < 2; ++jd)
            vf[jd] = *(const s16x8*)(vb + (jd*16+lrow)*64 + kc*32 + quad*8);
        #pragma unroll
        for (int i = 0; i < 4; ++i) {
            s16x8 pf = *(const s16x8*)(pl + (i*16+lrow)*72 + kc*32 + quad*8);
            #pragma unroll
            for (int jd = 0; jd < 2; ++jd)
                oacc[i][jd] = __builtin_amdgcn_mfma_f32_16x16x32_bf16(pf, vf[jd], oacc[i][jd], 0, 0, 0);
        }
    }
    unsigned short* ob = ao + (size_t)b_*12288 + h*32;
    #pragma unroll
    for (int i = 0; i < 4; ++i)
        #pragma unroll
        for (int jd = 0; jd < 2; ++jd)
            #pragma unroll
            for (int rg = 0; rg < 4; ++rg) {
                int n = i*16 + quad*4 + rg;
                ob[(size_t)n*192 + jd*16 + lrow] = f2bf(oacc[i][jd][rg]);
            }
}

// ---------------- proj GEMM + window-reverse + roll + residual -> x1 fp32 ----------------
__global__ __launch_bounds__(256) void gemm_proj_kernel(
    const unsigned short* __restrict__ A, const unsigned short* __restrict__ Wm,
    const float* __restrict__ bias, const float* __restrict__ x, float* __restrict__ x1)
{
    __shared__ __attribute__((aligned(16))) unsigned short As[64*200];
    __shared__ __attribute__((aligned(16))) unsigned short Bs[64*200];
    int m0 = blockIdx.y*64, o0 = blockIdx.x*64;
    f32x4 acc[4];
    gemm_mainloop(A, Wm, 192, m0, o0, As, Bs, acc);
    int tid = threadIdx.x, wave = tid >> 6, lane = tid & 63, lrow = lane & 15, quad = lane >> 4;
    int b_ = blockIdx.y;
    int bb = b_ >> 8, wi = b_ & 255, wh = wi >> 4, ww = wi & 15;
    #pragma unroll
    for (int j = 0; j < 4; ++j) {
        int o = o0 + j*16 + lrow;
        float bv = bias[o];
        #pragma unroll
        for (int rg = 0; rg < 4; ++rg) {
            int n = wave*16 + quad*4 + rg;
            int r = n >> 3, c = n & 7;
            int h = (wh*8 + r + 4) & 127;   // roll(+4) back
            int w = (ww*8 + c + 4) & 127;
            size_t addr = (((size_t)bb*128 + h)*128 + w)*192 + o;
            x1[addr] = x[addr] + acc[j][rg] + bv;
        }
    }
}

// ---------------- FC1 GEMM + bias + exact GELU -> h1 bf16 ----------------
__global__ __launch_bounds__(256) void gemm_fc1_kernel(
    const unsigned short* __restrict__ A, const unsigned short* __restrict__ Wm,
    const float* __restrict__ bias, unsigned short* __restrict__ h1)
{
    __shared__ __attribute__((aligned(16))) unsigned short As[64*200];
    __shared__ __attribute__((aligned(16))) unsigned short Bs[64*200];
    int m0 = blockIdx.y*64, o0 = blockIdx.x*64;
    f32x4 acc[4];
    gemm_mainloop(A, Wm, 192, m0, o0, As, Bs, acc);
    int tid = threadIdx.x, wave = tid >> 6, lane = tid & 63, lrow = lane & 15, quad = lane >> 4;
    #pragma unroll
    for (int j = 0; j < 4; ++j) {
        int o = o0 + j*16 + lrow;
        float bv = bias[o];
        #pragma unroll
        for (int rg = 0; rg < 4; ++rg) {
            int m = m0 + wave*16 + quad*4 + rg;
            float v = acc[j][rg] + bv;
            v = 0.5f * v * (1.0f + erff(v * 0.7071067811865475f));
            h1[(size_t)m*768 + o] = f2bf(v);
        }
    }
}

// ---------------- FC2 GEMM (K=768) + bias + residual -> out fp32 ----------------
__global__ __launch_bounds__(256) void gemm_fc2_kernel(
    const unsigned short* __restrict__ A, const unsigned short* __restrict__ Wm,
    const float* __restrict__ bias, const float* __restrict__ x1, float* __restrict__ out)
{
    __shared__ __attribute__((aligned(16))) unsigned short As[64*200];
    __shared__ __attribute__((aligned(16))) unsigned short Bs[64*200];
    int m0 = blockIdx.y*64, o0 = blockIdx.x*64;
    f32x4 acc[4];
    gemm_mainloop(A, Wm, 768, m0, o0, As, Bs, acc);
    int tid = threadIdx.x, wave = tid >> 6, lane = tid & 63, lrow = lane & 15, quad = lane >> 4;
    #pragma unroll
    for (int j = 0; j < 4; ++j) {
        int o = o0 + j*16 + lrow;
        float bv = bias[o];
        #pragma unroll
        for (int rg = 0; rg < 4; ++rg) {
            int m = m0 + wave*16 + quad*4 + rg;
            size_t ad = (size_t)m*192 + o;
            out[ad] = x1[ad] + acc[j][rg] + bv;
        }
    }
}

extern "C" void kernel_launch(void* const* d_in, const int* in_sizes, int n_in,
                              void* d_out, int out_size, void* d_ws, size_t ws_size,
                              hipStream_t stream)
{
    const float* x      = (const float*)d_in[0];
    const float* g1     = (const float*)d_in[1];
    const float* b1     = (const float*)d_in[2];
    const float* qkv_w  = (const float*)d_in[3];
    const float* qkv_b  = (const float*)d_in[4];
    const float* rpb    = (const float*)d_in[5];
    const float* proj_w = (const float*)d_in[6];
    const float* proj_b = (const float*)d_in[7];
    const float* g2     = (const float*)d_in[8];
    const float* b2     = (const float*)d_in[9];
    const float* fc1_w  = (const float*)d_in[10];
    const float* fc1_b  = (const float*)d_in[11];
    const float* fc2_w  = (const float*)d_in[12];
    const float* fc2_b  = (const float*)d_in[13];
    float* out = (float*)d_out;
    char* ws = (char*)d_ws;

    if (ws_size < 353206272ULL) return;  // need ~353 MB

    // workspace layout (lifetime-overlapped):
    unsigned short* win  = (unsigned short*)(ws + 0);           // 50.3MB  [dies after qkv]
    unsigned short* qbuf = (unsigned short*)(ws + 50331648);    // 50.3MB  [dies after attn]
    unsigned short* kbuf = (unsigned short*)(ws + 100663296);   // 50.3MB
    unsigned short* vbuf = (unsigned short*)(ws + 150994944);   // 50.3MB (transposed [d][n])
    unsigned short* attn = (unsigned short*)(ws + 201326592);   // 50.3MB  [dies after proj]
    float*          x1   = (float*)        (ws + 251658240);    // 100.7MB [persists]
    unsigned short* wq   = (unsigned short*)(ws + 352321536);
    unsigned short* wp   = (unsigned short*)(ws + 352321536 + 221184);
    unsigned short* w1   = (unsigned short*)(ws + 352321536 + 221184 + 73728);
    unsigned short* w2   = (unsigned short*)(ws + 352321536 + 221184 + 73728 + 294912);
    unsigned short* h1   = (unsigned short*)(ws + 0);           // 201.3MB overlays win+q+k+v
    unsigned short* xln2 = attn;                                 // overlays attn after proj

    wconv_all<<<576, 256, 0, stream>>>(qkv_w, proj_w, fc1_w, fc2_w, wq, wp, w1, w2);
    ln1_win_kernel<<<TOK/4, 256, 0, stream>>>(x, g1, b1, win);
    gemm_qkv_kernel<<<dim3(9, 2048), 256, 0, stream>>>(win, wq, qkv_b, qbuf, kbuf, vbuf);
    attn_kernel<<<2048, 384, 0, stream>>>(qbuf, kbuf, vbuf, rpb, attn);
    gemm_proj_kernel<<<dim3(3, 2048), 256, 0, stream>>>(attn, wp, proj_b, x, x1);
    ln2_kernel<<<TOK/4, 256, 0, stream>>>(x1, g2, b2, xln2);
    gemm_fc1_kernel<<<dim3(12, 2048), 256, 0, stream>>>(xln2, w1, fc1_b, h1);
    gemm_fc2_kernel<<<dim3(3, 2048), 256, 0, stream>>>(h1, w2, fc2_b, x1, out);
}

// Round 2
// 673.500 us; speedup vs baseline: 1.0036x; 1.0036x over previous
//
#include <hip/hip_runtime.h>
#include <hip/hip_bf16.h>

typedef __attribute__((ext_vector_type(8))) short s16x8;
typedef __attribute__((ext_vector_type(4))) float f32x4;

#define TOK 131072   // 8*128*128 tokens

__device__ __forceinline__ unsigned short f2bf(float f){
    __hip_bfloat16 h = __float2bfloat16(f);
    return *reinterpret_cast<unsigned short*>(&h);
}

__device__ __forceinline__ int flab(int g){ return (g < 120) ? 0 : ((g < 124) ? 1 : 2); }

// async global->LDS, 16B per lane; LDS dest = wave-uniform base + lane*16
__device__ __forceinline__ void async16(const void* g, void* l){
    __builtin_amdgcn_global_load_lds(
        (const __attribute__((address_space(1))) unsigned int*)g,
        (__attribute__((address_space(3))) unsigned int*)l, 16, 0, 0);
}

// ---------------- weight fp32 -> bf16 ----------------
__global__ __launch_bounds__(256) void wconv_all(
    const float* __restrict__ w0, const float* __restrict__ w1,
    const float* __restrict__ w2, const float* __restrict__ w3,
    unsigned short* __restrict__ o0, unsigned short* __restrict__ o1,
    unsigned short* __restrict__ o2, unsigned short* __restrict__ o3)
{
    int i = blockIdx.x*256 + threadIdx.x;
    if (i < 110592) o0[i] = f2bf(w0[i]);   // qkv_w 576x192
    if (i < 36864)  o1[i] = f2bf(w1[i]);   // proj_w 192x192
    if (i < 147456) o2[i] = f2bf(w2[i]);   // fc1_w 768x192
    if (i < 147456) o3[i] = f2bf(w3[i]);   // fc2_w 192x768
}

// ---------------- LN1 + shift + window partition -> bf16 ----------------
__global__ __launch_bounds__(256) void ln1_win_kernel(
    const float* __restrict__ x, const float* __restrict__ g,
    const float* __restrict__ b, unsigned short* __restrict__ win)
{
    int wid  = blockIdx.x*4 + (threadIdx.x >> 6);
    int lane = threadIdx.x & 63;
    int b_ = wid >> 6, n = wid & 63;
    int bb = b_ >> 8, wi = b_ & 255;
    int wh = wi >> 4, ww = wi & 15;
    int r = n >> 3, c = n & 7;
    int h = (wh*8 + r + 4) & 127;   // roll(-4)
    int w = (ww*8 + c + 4) & 127;
    const float* px = x + (((size_t)bb*128 + h)*128 + w)*192;
    float v0 = px[lane], v1 = px[lane+64], v2 = px[lane+128];
    float s = v0 + v1 + v2;
    #pragma unroll
    for (int o = 1; o < 64; o <<= 1) s += __shfl_xor(s, o);
    float mu = s * (1.0f/192.0f);
    float d0 = v0-mu, d1 = v1-mu, d2 = v2-mu;
    float qv = d0*d0 + d1*d1 + d2*d2;
    #pragma unroll
    for (int o = 1; o < 64; o <<= 1) qv += __shfl_xor(qv, o);
    float rstd = rsqrtf(qv * (1.0f/192.0f) + 1e-5f);
    unsigned short* pw = win + (size_t)wid*192;
    pw[lane]     = f2bf(d0*rstd*g[lane]     + b[lane]);
    pw[lane+64]  = f2bf(d1*rstd*g[lane+64]  + b[lane+64]);
    pw[lane+128] = f2bf(d2*rstd*g[lane+128] + b[lane+128]);
}

// ---------------- LN2 ----------------
__global__ __launch_bounds__(256) void ln2_kernel(
    const float* __restrict__ x1, const float* __restrict__ g,
    const float* __restrict__ b, unsigned short* __restrict__ out)
{
    int t = blockIdx.x*4 + (threadIdx.x >> 6);
    int lane = threadIdx.x & 63;
    const float* px = x1 + (size_t)t*192;
    float v0 = px[lane], v1 = px[lane+64], v2 = px[lane+128];
    float s = v0 + v1 + v2;
    #pragma unroll
    for (int o = 1; o < 64; o <<= 1) s += __shfl_xor(s, o);
    float mu = s * (1.0f/192.0f);
    float d0 = v0-mu, d1 = v1-mu, d2 = v2-mu;
    float qv = d0*d0 + d1*d1 + d2*d2;
    #pragma unroll
    for (int o = 1; o < 64; o <<= 1) qv += __shfl_xor(qv, o);
    float rstd = rsqrtf(qv * (1.0f/192.0f) + 1e-5f);
    unsigned short* pw = out + (size_t)t*192;
    pw[lane]     = f2bf(d0*rstd*g[lane]     + b[lane]);
    pw[lane+64]  = f2bf(d1*rstd*g[lane+64]  + b[lane+64]);
    pw[lane+128] = f2bf(d2*rstd*g[lane+128] + b[lane+128]);
}

// =====================================================================
// 256x64-tile GEMM mainloop: C[256x64] = A[m0..][K] * W[o0..][K]^T
// 256 thr = 4 waves stacked on M (wave wv owns rows wv*64..+63, all 64 cols)
// LDS: As[256][64] + Bs[64][64] bf16, XOR-swizzled: slot(row,blk) holds
// global (row, blk^(row&7)) [16B blocks] -> conflict-free ds_read_b128.
// Staged via global_load_lds width=16 (no padding allowed -> swizzle).
// acc[i][j]: element (m = m0+wv*64+i*16+quad*4+rg, o = o0+j*16+lrow)
// =====================================================================
__device__ __forceinline__ void mm256x64(
    const unsigned short* __restrict__ A, const unsigned short* __restrict__ W,
    int K, int m0, int o0, unsigned short* As, unsigned short* Bs,
    f32x4 (&acc)[4][4])
{
    const int tid = threadIdx.x, wv = tid >> 6, lane = tid & 63;
    const int lrow = lane & 15, quad = lane >> 4;
    const int lr8 = lane >> 3, lb = lane & 7;
    const int sb = ((lb ^ lr8) << 3);                 // swizzled col (elements)
    #pragma unroll
    for (int i = 0; i < 4; ++i)
        #pragma unroll
        for (int j = 0; j < 4; ++j) acc[i][j] = (f32x4){0.f,0.f,0.f,0.f};

    const unsigned short* Abase = A + (size_t)(m0 + wv*8 + lr8)*K + sb;
    const unsigned short* Wbase = W + (size_t)(o0 + wv*8 + lr8)*K + sb;

    for (int k0 = 0; k0 < K; k0 += 64) {
        #pragma unroll
        for (int it = 0; it < 8; ++it)
            async16(Abase + (size_t)(it*32)*K + k0, As + (it*4 + wv)*512);
        #pragma unroll
        for (int it = 0; it < 2; ++it)
            async16(Wbase + (size_t)(it*32)*K + k0, Bs + (it*4 + wv)*512);
        __syncthreads();
        #pragma unroll
        for (int kc = 0; kc < 2; ++kc) {
            const int blk = quad + 4*kc;
            s16x8 af[4], bf[4];
            #pragma unroll
            for (int i = 0; i < 4; ++i) {
                int row = wv*64 + i*16 + lrow;
                af[i] = *(const s16x8*)(As + row*64 + ((blk ^ (row & 7)) << 3));
            }
            #pragma unroll
            for (int j = 0; j < 4; ++j) {
                int row = j*16 + lrow;
                bf[j] = *(const s16x8*)(Bs + row*64 + ((blk ^ (row & 7)) << 3));
            }
            #pragma unroll
            for (int i = 0; i < 4; ++i)
                #pragma unroll
                for (int j = 0; j < 4; ++j)
                    acc[i][j] = __builtin_amdgcn_mfma_f32_16x16x32_bf16(af[i], bf[j], acc[i][j], 0, 0, 0);
        }
        __syncthreads();
    }
}

// ---------------- QKV: win[131072,192] x qkv_w[576,192]^T ----------------
__global__ __launch_bounds__(256) void gemm_qkv_kernel(
    const unsigned short* __restrict__ A, const unsigned short* __restrict__ Wm,
    const float* __restrict__ bias, unsigned short* __restrict__ qo,
    unsigned short* __restrict__ ko, unsigned short* __restrict__ vo)
{
    __shared__ __attribute__((aligned(16))) char smem[40960];
    unsigned short* As = (unsigned short*)smem;
    unsigned short* Bs = (unsigned short*)(smem + 32768);
    const int m0 = blockIdx.y*256, o0 = blockIdx.x*64;
    f32x4 acc[4][4];
    mm256x64(A, Wm, 192, m0, o0, As, Bs, acc);
    const int tid = threadIdx.x, wv = tid >> 6, lane = tid & 63;
    const int lrow = lane & 15, quad = lane >> 4;
    const int part = o0 / 192;        // 0=q 1=k 2=v
    float bv[4];
    #pragma unroll
    for (int j = 0; j < 4; ++j) bv[j] = bias[o0 + j*16 + lrow];

    if (part < 2) {
        unsigned short* dst = (part == 0) ? qo : ko;
        const float scale = (part == 0) ? 0.17677669529663687f : 1.0f;
        unsigned short* T = (unsigned short*)smem;     // [256][72]
        #pragma unroll
        for (int i = 0; i < 4; ++i)
            #pragma unroll
            for (int j = 0; j < 4; ++j)
                #pragma unroll
                for (int rg = 0; rg < 4; ++rg) {
                    int ml = wv*64 + i*16 + quad*4 + rg;
                    T[ml*72 + j*16 + lrow] = f2bf((acc[i][j][rg] + bv[j]) * scale);
                }
        __syncthreads();
        for (int c = tid; c < 2048; c += 256) {
            int row = c >> 3, blk = c & 7;
            int m = m0 + row, b_ = m >> 6, n = m & 63;
            int o_in = o0 + blk*8 - part*192;
            int head = o_in >> 5, d = o_in & 31;
            *(int4*)(dst + ((size_t)(b_*6 + head)*64 + n)*32 + d) =
                *(const int4*)(T + row*72 + blk*8);
        }
    } else {
        // v: store transposed [b_,h][d][n]; LDS T[col 64][m 264pad]
        unsigned short* T = (unsigned short*)smem;
        #pragma unroll
        for (int i = 0; i < 4; ++i)
            #pragma unroll
            for (int j = 0; j < 4; ++j)
                #pragma unroll
                for (int rg = 0; rg < 4; ++rg) {
                    int ml = wv*64 + i*16 + quad*4 + rg;
                    T[(j*16 + lrow)*264 + ml] = f2bf(acc[i][j][rg] + bv[j]);
                }
        __syncthreads();
        for (int c = tid; c < 2048; c += 256) {
            int col = c >> 5, mb = c & 31;
            int b_ = (m0 >> 6) + (mb >> 3), n = (mb & 7) * 8;
            int o_in = o0 + col - 384;
            int head = o_in >> 5, d = o_in & 31;
            *(int4*)(vo + ((size_t)(b_*6 + head)*32 + d)*64 + n) =
                *(const int4*)(T + col*264 + mb*8);
        }
    }
}

// ---------------- windowed attention: 1 block/window, 6 waves = 6 heads ----------------
__global__ __launch_bounds__(384) void attn_kernel(
    const unsigned short* __restrict__ q, const unsigned short* __restrict__ k,
    const unsigned short* __restrict__ vT, const float* __restrict__ rpb,
    unsigned short* __restrict__ ao)
{
    __shared__ float rpb_s[1350];
    __shared__ __attribute__((aligned(16))) unsigned short p_lds[6*4608];
    const int b_ = blockIdx.x;
    const int h = threadIdx.x >> 6;
    const int lane = threadIdx.x & 63, lrow = lane & 15, quad = lane >> 4;
    for (int i = threadIdx.x; i < 1350; i += 384) rpb_s[i] = rpb[i];
    __syncthreads();

    const size_t hb = ((size_t)b_*6 + h)*2048;
    const unsigned short* qb = q  + hb;
    const unsigned short* kb = k  + hb;
    const unsigned short* vb = vT + hb;

    s16x8 qf[4], kf[4];
    #pragma unroll
    for (int i = 0; i < 4; ++i) qf[i] = *(const s16x8*)(qb + (i*16+lrow)*32 + quad*8);
    #pragma unroll
    for (int j = 0; j < 4; ++j) kf[j] = *(const s16x8*)(kb + (j*16+lrow)*32 + quad*8);

    const f32x4 zz = {0.f,0.f,0.f,0.f};
    f32x4 s[4][4];
    #pragma unroll
    for (int i = 0; i < 4; ++i)
        #pragma unroll
        for (int j = 0; j < 4; ++j)
            s[i][j] = __builtin_amdgcn_mfma_f32_16x16x32_bf16(qf[i], kf[j], zz, 0, 0, 0);

    const int wi = b_ & 255, wh = wi >> 4, ww = wi & 15;
    int labm[4];
    #pragma unroll
    for (int j = 0; j < 4; ++j) {
        int m = j*16 + lrow;
        labm[j] = flab(wh*8 + (m >> 3))*3 + flab(ww*8 + (m & 7));
    }
    unsigned short* pl = p_lds + h*4608;
    #pragma unroll
    for (int i = 0; i < 4; ++i) {
        #pragma unroll
        for (int rg = 0; rg < 4; ++rg) {
            int n = i*16 + quad*4 + rg;
            int rn = n >> 3, cn = n & 7;
            int labn = flab(wh*8 + rn)*3 + flab(ww*8 + cn);
            float vals[4];
            float vmax = -1e30f;
            #pragma unroll
            for (int j = 0; j < 4; ++j) {
                int m = j*16 + lrow;
                int idx = ((rn - (m >> 3) + 7)*15 + (cn - (m & 7) + 7))*6 + h;
                float val = s[i][j][rg] + rpb_s[idx];
                if (labn != labm[j]) val -= 100.f;
                vals[j] = val;
                vmax = fmaxf(vmax, val);
            }
            #pragma unroll
            for (int o = 1; o < 16; o <<= 1) vmax = fmaxf(vmax, __shfl_xor(vmax, o));
            float sum = 0.f;
            #pragma unroll
            for (int j = 0; j < 4; ++j) { vals[j] = __expf(vals[j] - vmax); sum += vals[j]; }
            #pragma unroll
            for (int o = 1; o < 16; o <<= 1) sum += __shfl_xor(sum, o);
            float inv = 1.f / sum;
            #pragma unroll
            for (int j = 0; j < 4; ++j) pl[n*72 + j*16 + lrow] = f2bf(vals[j]*inv);
        }
    }
    __syncthreads();

    f32x4 oacc[4][2];
    #pragma unroll
    for (int i = 0; i < 4; ++i) { oacc[i][0] = zz; oacc[i][1] = zz; }
    #pragma unroll
    for (int kc = 0; kc < 2; ++kc) {
        s16x8 vf[2];
        #pragma unroll
        for (int jd = 0; jd < 2; ++jd)
            vf[jd] = *(const s16x8*)(vb + (jd*16+lrow)*64 + kc*32 + quad*8);
        #pragma unroll
        for (int i = 0; i < 4; ++i) {
            s16x8 pf = *(const s16x8*)(pl + (i*16+lrow)*72 + kc*32 + quad*8);
            #pragma unroll
            for (int jd = 0; jd < 2; ++jd)
                oacc[i][jd] = __builtin_amdgcn_mfma_f32_16x16x32_bf16(pf, vf[jd], oacc[i][jd], 0, 0, 0);
        }
    }
    unsigned short* ob = ao + (size_t)b_*12288 + h*32;
    #pragma unroll
    for (int i = 0; i < 4; ++i)
        #pragma unroll
        for (int jd = 0; jd < 2; ++jd)
            #pragma unroll
            for (int rg = 0; rg < 4; ++rg) {
                int n = i*16 + quad*4 + rg;
                ob[(size_t)n*192 + jd*16 + lrow] = f2bf(oacc[i][jd][rg]);
            }
}

// ---------------- proj + window-reverse + roll + residual -> x1 fp32 ----------------
__global__ __launch_bounds__(256) void gemm_proj_kernel(
    const unsigned short* __restrict__ A, const unsigned short* __restrict__ Wm,
    const float* __restrict__ bias, const float* __restrict__ x, float* __restrict__ x1)
{
    __shared__ __attribute__((aligned(16))) char smem[40960];
    unsigned short* As = (unsigned short*)smem;
    unsigned short* Bs = (unsigned short*)(smem + 32768);
    const int m0 = blockIdx.y*256, o0 = blockIdx.x*64;
    f32x4 acc[4][4];
    mm256x64(A, Wm, 192, m0, o0, As, Bs, acc);
    const int tid = threadIdx.x, wv = tid >> 6, lane = tid & 63;
    const int lrow = lane & 15, quad = lane >> 4;
    float bv[4];
    #pragma unroll
    for (int j = 0; j < 4; ++j) bv[j] = bias[o0 + j*16 + lrow];
    float* T = (float*)smem;                        // [128][68]
    #pragma unroll
    for (int pass = 0; pass < 2; ++pass) {
        __syncthreads();
        if ((wv >> 1) == pass) {
            int wl = wv & 1;
            #pragma unroll
            for (int i = 0; i < 4; ++i)
                #pragma unroll
                for (int j = 0; j < 4; ++j)
                    #pragma unroll
                    for (int rg = 0; rg < 4; ++rg)
                        T[(wl*64 + i*16 + quad*4 + rg)*68 + j*16 + lrow] = acc[i][j][rg] + bv[j];
        }
        __syncthreads();
        for (int c = tid; c < 2048; c += 256) {
            int row = c >> 4, blk = c & 15;
            int m = m0 + pass*128 + row;
            int b_ = m >> 6, n = m & 63;
            int bb = b_ >> 8, wi = b_ & 255, wh = wi >> 4, ww = wi & 15;
            int r = n >> 3, cc = n & 7;
            int hh = (wh*8 + r + 4) & 127;
            int wwp = (ww*8 + cc + 4) & 127;
            size_t addr = (((size_t)bb*128 + hh)*128 + wwp)*192 + o0 + blk*4;
            float4 v = *(const float4*)(T + row*68 + blk*4);
            float4 rx = *(const float4*)(x + addr);
            v.x += rx.x; v.y += rx.y; v.z += rx.z; v.w += rx.w;
            *(float4*)(x1 + addr) = v;
        }
    }
}

// ---------------- FC1 + bias + exact GELU -> h1 bf16 ----------------
__global__ __launch_bounds__(256) void gemm_fc1_kernel(
    const unsigned short* __restrict__ A, const unsigned short* __restrict__ Wm,
    const float* __restrict__ bias, unsigned short* __restrict__ h1)
{
    __shared__ __attribute__((aligned(16))) char smem[40960];
    unsigned short* As = (unsigned short*)smem;
    unsigned short* Bs = (unsigned short*)(smem + 32768);
    const int m0 = blockIdx.y*256, o0 = blockIdx.x*64;
    f32x4 acc[4][4];
    mm256x64(A, Wm, 192, m0, o0, As, Bs, acc);
    const int tid = threadIdx.x, wv = tid >> 6, lane = tid & 63;
    const int lrow = lane & 15, quad = lane >> 4;
    float bv[4];
    #pragma unroll
    for (int j = 0; j < 4; ++j) bv[j] = bias[o0 + j*16 + lrow];
    unsigned short* T = (unsigned short*)smem;      // [256][72]
    #pragma unroll
    for (int i = 0; i < 4; ++i)
        #pragma unroll
        for (int j = 0; j < 4; ++j)
            #pragma unroll
            for (int rg = 0; rg < 4; ++rg) {
                int ml = wv*64 + i*16 + quad*4 + rg;
                float v = acc[i][j][rg] + bv[j];
                v = 0.5f * v * (1.0f + erff(v * 0.7071067811865475f));
                T[ml*72 + j*16 + lrow] = f2bf(v);
            }
    __syncthreads();
    for (int c = tid; c < 2048; c += 256) {
        int row = c >> 3, blk = c & 7;
        *(int4*)(h1 + (size_t)(m0 + row)*768 + o0 + blk*8) =
            *(const int4*)(T + row*72 + blk*8);
    }
}

// ---------------- FC2 (K=768) + bias + residual -> out fp32 ----------------
__global__ __launch_bounds__(256) void gemm_fc2_kernel(
    const unsigned short* __restrict__ A, const unsigned short* __restrict__ Wm,
    const float* __restrict__ bias, const float* __restrict__ x1, float* __restrict__ out)
{
    __shared__ __attribute__((aligned(16))) char smem[40960];
    unsigned short* As = (unsigned short*)smem;
    unsigned short* Bs = (unsigned short*)(smem + 32768);
    const int m0 = blockIdx.y*256, o0 = blockIdx.x*64;
    f32x4 acc[4][4];
    mm256x64(A, Wm, 768, m0, o0, As, Bs, acc);
    const int tid = threadIdx.x, wv = tid >> 6, lane = tid & 63;
    const int lrow = lane & 15, quad = lane >> 4;
    float bv[4];
    #pragma unroll
    for (int j = 0; j < 4; ++j) bv[j] = bias[o0 + j*16 + lrow];
    float* T = (float*)smem;                        // [128][68]
    #pragma unroll
    for (int pass = 0; pass < 2; ++pass) {
        __syncthreads();
        if ((wv >> 1) == pass) {
            int wl = wv & 1;
            #pragma unroll
            for (int i = 0; i < 4; ++i)
                #pragma unroll
                for (int j = 0; j < 4; ++j)
                    #pragma unroll
                    for (int rg = 0; rg < 4; ++rg)
                        T[(wl*64 + i*16 + quad*4 + rg)*68 + j*16 + lrow] = acc[i][j][rg] + bv[j];
        }
        __syncthreads();
        for (int c = tid; c < 2048; c += 256) {
            int row = c >> 4, blk = c & 15;
            size_t addr = (size_t)(m0 + pass*128 + row)*192 + o0 + blk*4;
            float4 v = *(const float4*)(T + row*68 + blk*4);
            float4 rx = *(const float4*)(x1 + addr);
            v.x += rx.x; v.y += rx.y; v.z += rx.z; v.w += rx.w;
            *(float4*)(out + addr) = v;
        }
    }
}

extern "C" void kernel_launch(void* const* d_in, const int* in_sizes, int n_in,
                              void* d_out, int out_size, void* d_ws, size_t ws_size,
                              hipStream_t stream)
{
    const float* x      = (const float*)d_in[0];
    const float* g1     = (const float*)d_in[1];
    const float* b1     = (const float*)d_in[2];
    const float* qkv_w  = (const float*)d_in[3];
    const float* qkv_b  = (const float*)d_in[4];
    const float* rpb    = (const float*)d_in[5];
    const float* proj_w = (const float*)d_in[6];
    const float* proj_b = (const float*)d_in[7];
    const float* g2     = (const float*)d_in[8];
    const float* b2     = (const float*)d_in[9];
    const float* fc1_w  = (const float*)d_in[10];
    const float* fc1_b  = (const float*)d_in[11];
    const float* fc2_w  = (const float*)d_in[12];
    const float* fc2_b  = (const float*)d_in[13];
    float* out = (float*)d_out;
    char* ws = (char*)d_ws;

    if (ws_size < 353206272ULL) return;

    unsigned short* win  = (unsigned short*)(ws + 0);
    unsigned short* qbuf = (unsigned short*)(ws + 50331648);
    unsigned short* kbuf = (unsigned short*)(ws + 100663296);
    unsigned short* vbuf = (unsigned short*)(ws + 150994944);
    unsigned short* attn = (unsigned short*)(ws + 201326592);
    float*          x1   = (float*)        (ws + 251658240);
    unsigned short* wq   = (unsigned short*)(ws + 352321536);
    unsigned short* wp   = (unsigned short*)(ws + 352321536 + 221184);
    unsigned short* w1   = (unsigned short*)(ws + 352321536 + 221184 + 73728);
    unsigned short* w2   = (unsigned short*)(ws + 352321536 + 221184 + 73728 + 294912);
    unsigned short* h1   = (unsigned short*)(ws + 0);        // overlays win+q+k+v
    unsigned short* xln2 = attn;

    wconv_all<<<576, 256, 0, stream>>>(qkv_w, proj_w, fc1_w, fc2_w, wq, wp, w1, w2);
    ln1_win_kernel<<<TOK/4, 256, 0, stream>>>(x, g1, b1, win);
    gemm_qkv_kernel<<<dim3(9, 512), 256, 0, stream>>>(win, wq, qkv_b, qbuf, kbuf, vbuf);
    attn_kernel<<<2048, 384, 0, stream>>>(qbuf, kbuf, vbuf, rpb, attn);
    gemm_proj_kernel<<<dim3(3, 512), 256, 0, stream>>>(attn, wp, proj_b, x, x1);
    ln2_kernel<<<TOK/4, 256, 0, stream>>>(x1, g2, b2, xln2);
    gemm_fc1_kernel<<<dim3(12, 512), 256, 0, stream>>>(xln2, w1, fc1_b, h1);
    gemm_fc2_kernel<<<dim3(3, 512), 256, 0, stream>>>(h1, w2, fc2_b, x1, out);
}

// Round 3
// 591.314 us; speedup vs baseline: 1.1431x; 1.1390x over previous
//
#include <hip/hip_runtime.h>
#include <hip/hip_bf16.h>

typedef __attribute__((ext_vector_type(8))) short s16x8;
typedef __attribute__((ext_vector_type(4))) float f32x4;

__device__ __forceinline__ unsigned short f2bf(float f){
    __hip_bfloat16 h = __float2bfloat16(f);
    return *reinterpret_cast<unsigned short*>(&h);
}

__device__ __forceinline__ int flab(int g){ return (g < 120) ? 0 : ((g < 124) ? 1 : 2); }

// async global->LDS, 16B per lane; LDS dest = wave-uniform base + lane*16
__device__ __forceinline__ void async16(const void* g, void* l){
    __builtin_amdgcn_global_load_lds(
        (const __attribute__((address_space(1))) unsigned int*)g,
        (__attribute__((address_space(3))) unsigned int*)l, 16, 0, 0);
}

// ---------------- weight fp32 -> bf16 ----------------
__global__ __launch_bounds__(256) void wconv_all(
    const float* __restrict__ w0, const float* __restrict__ w1,
    const float* __restrict__ w2, const float* __restrict__ w3,
    unsigned short* __restrict__ o0, unsigned short* __restrict__ o1,
    unsigned short* __restrict__ o2, unsigned short* __restrict__ o3)
{
    int i = blockIdx.x*256 + threadIdx.x;
    if (i < 110592) o0[i] = f2bf(w0[i]);   // qkv_w 576x192
    if (i < 36864)  o1[i] = f2bf(w1[i]);   // proj_w 192x192
    if (i < 147456) o2[i] = f2bf(w2[i]);   // fc1_w 768x192
    if (i < 147456) o3[i] = f2bf(w3[i]);   // fc2_w 192x768
}

// =====================================================================
// LN1 + shift + window partition + QKV GEMM, fused. One block per window.
// A-tile (64x192 LN'd bf16) LDS-resident across all 9 o-tiles; weights
// streamed per o-tile (L2-hot). q scaled; v stored transposed [b,h][d][n].
// =====================================================================
__global__ __launch_bounds__(256) void lnqkv_kernel(
    const float* __restrict__ x, const float* __restrict__ g1, const float* __restrict__ b1,
    const unsigned short* __restrict__ wq, const float* __restrict__ qkvb,
    unsigned short* __restrict__ qo, unsigned short* __restrict__ ko,
    unsigned short* __restrict__ vo)
{
    __shared__ __attribute__((aligned(16))) unsigned short win[64*200];  // 25.6KB
    __shared__ __attribute__((aligned(16))) unsigned short Bs[64*200];   // 25.6KB (B-tile / T)
    const int b_ = blockIdx.x;
    const int bb = b_>>8, wi = b_&255, wh = wi>>4, ww = wi&15;
    const int tid = threadIdx.x;
    const int wv = tid>>6, lane = tid&63, lrow = lane&15, quad = lane>>4;

    // ---- LN1: thread t -> token n = t>>2, quarter q4 = t&3 (48 ch each) ----
    {
        const int n = tid>>2, q4 = tid&3;
        const int r = n>>3, c = n&7;
        const int hh = (wh*8 + r + 4)&127, wp = (ww*8 + c + 4)&127;  // roll(-4)
        const float* px = x + (((size_t)bb*128+hh)*128+wp)*192 + q4*48;
        float v[48];
        #pragma unroll
        for (int m=0;m<12;++m) *(float4*)(v+m*4) = *(const float4*)(px+m*4);
        float s = 0.f;
        #pragma unroll
        for (int k=0;k<48;++k) s += v[k];
        s += __shfl_xor(s,1); s += __shfl_xor(s,2);
        float mu = s*(1.0f/192.0f);
        float qv = 0.f;
        #pragma unroll
        for (int k=0;k<48;++k){ float d=v[k]-mu; qv += d*d; }
        qv += __shfl_xor(qv,1); qv += __shfl_xor(qv,2);
        float rstd = rsqrtf(qv*(1.0f/192.0f) + 1e-5f);
        const float* pg = g1 + q4*48;
        const float* pb = b1 + q4*48;
        unsigned short* pw = win + n*200 + q4*48;
        #pragma unroll
        for (int k=0;k<48;++k) pw[k] = f2bf((v[k]-mu)*rstd*pg[k] + pb[k]);
    }
    __syncthreads();

    // hoist A fragments (reused by every o-tile)
    s16x8 af[6];
    #pragma unroll
    for (int kc=0;kc<6;++kc)
        af[kc] = *(const s16x8*)(win + (wv*16+lrow)*200 + kc*32 + quad*8);

    for (int ot=0; ot<9; ++ot) {
        const int o0 = ot*64;
        __syncthreads();                       // Bs free (prev T reads done)
        #pragma unroll
        for (int t=0;t<6;++t) {
            int cid = tid + t*256;             // 0..1535, globally contiguous
            *(int4*)(Bs + (cid/24)*200 + (cid%24)*8) =
                *(const int4*)(wq + (size_t)o0*192 + cid*8);
        }
        __syncthreads();
        f32x4 acc[4];
        #pragma unroll
        for (int j=0;j<4;++j) acc[j] = (f32x4){0.f,0.f,0.f,0.f};
        #pragma unroll
        for (int kc=0;kc<6;++kc)
            #pragma unroll
            for (int j=0;j<4;++j) {
                s16x8 bf = *(const s16x8*)(Bs + (j*16+lrow)*200 + kc*32 + quad*8);
                acc[j] = __builtin_amdgcn_mfma_f32_16x16x32_bf16(af[kc], bf, acc[j], 0, 0, 0);
            }
        __syncthreads();                       // done reading Bs; reuse as T
        unsigned short* T = Bs;
        const int part = ot/3;                 // 0=q 1=k 2=v
        float bv[4];
        #pragma unroll
        for (int j=0;j<4;++j) bv[j] = qkvb[o0 + j*16 + lrow];

        if (part < 2) {
            const float scale = (part==0) ? 0.17677669529663687f : 1.0f;
            #pragma unroll
            for (int j=0;j<4;++j)
                #pragma unroll
                for (int rg=0;rg<4;++rg) {
                    int n2 = wv*16 + quad*4 + rg;
                    T[n2*72 + j*16 + lrow] = f2bf((acc[j][rg]+bv[j])*scale);
                }
            __syncthreads();
            unsigned short* dst = (part==0) ? qo : ko;
            #pragma unroll
            for (int t=0;t<2;++t) {
                int c = tid + t*256;
                int n2 = c>>3, blk = c&7;
                int o_in = o0 + blk*8 - part*192;
                int head = o_in>>5, d = o_in&31;
                *(int4*)(dst + (((size_t)b_*6+head)*64 + n2)*32 + d) =
                    *(const int4*)(T + n2*72 + blk*8);
            }
        } else {
            #pragma unroll
            for (int j=0;j<4;++j)
                #pragma unroll
                for (int rg=0;rg<4;++rg) {
                    int n2 = wv*16 + quad*4 + rg;
                    T[(j*16+lrow)*72 + n2] = f2bf(acc[j][rg]+bv[j]);
                }
            __syncthreads();
            #pragma unroll
            for (int t=0;t<2;++t) {
                int c = tid + t*256;
                int ol = c>>3, nb = (c&7)*8;
                int o_in = o0 + ol - 384;
                int head = o_in>>5, d = o_in&31;
                *(int4*)(vo + (((size_t)b_*6+head)*32 + d)*64 + nb) =
                    *(const int4*)(T + ol*72 + nb);
            }
        }
    }
}

// ---------------- windowed attention: 1 block/window, 6 waves = 6 heads ----------------
__global__ __launch_bounds__(384) void attn_kernel(
    const unsigned short* __restrict__ q, const unsigned short* __restrict__ k,
    const unsigned short* __restrict__ vT, const float* __restrict__ rpb,
    unsigned short* __restrict__ ao)
{
    __shared__ float rpb_s[1350];
    __shared__ __attribute__((aligned(16))) unsigned short p_lds[6*4608];
    const int b_ = blockIdx.x;
    const int h = threadIdx.x >> 6;
    const int lane = threadIdx.x & 63, lrow = lane & 15, quad = lane >> 4;
    for (int i = threadIdx.x; i < 1350; i += 384) rpb_s[i] = rpb[i];
    __syncthreads();

    const size_t hb = ((size_t)b_*6 + h)*2048;
    const unsigned short* qb = q  + hb;
    const unsigned short* kb = k  + hb;
    const unsigned short* vb = vT + hb;

    s16x8 qf[4], kf[4];
    #pragma unroll
    for (int i = 0; i < 4; ++i) qf[i] = *(const s16x8*)(qb + (i*16+lrow)*32 + quad*8);
    #pragma unroll
    for (int j = 0; j < 4; ++j) kf[j] = *(const s16x8*)(kb + (j*16+lrow)*32 + quad*8);

    const f32x4 zz = {0.f,0.f,0.f,0.f};
    f32x4 s[4][4];
    #pragma unroll
    for (int i = 0; i < 4; ++i)
        #pragma unroll
        for (int j = 0; j < 4; ++j)
            s[i][j] = __builtin_amdgcn_mfma_f32_16x16x32_bf16(qf[i], kf[j], zz, 0, 0, 0);

    const int wi = b_ & 255, wh = wi >> 4, ww = wi & 15;
    int labm[4];
    #pragma unroll
    for (int j = 0; j < 4; ++j) {
        int m = j*16 + lrow;
        labm[j] = flab(wh*8 + (m >> 3))*3 + flab(ww*8 + (m & 7));
    }
    unsigned short* pl = p_lds + h*4608;
    #pragma unroll
    for (int i = 0; i < 4; ++i) {
        #pragma unroll
        for (int rg = 0; rg < 4; ++rg) {
            int n = i*16 + quad*4 + rg;
            int rn = n >> 3, cn = n & 7;
            int labn = flab(wh*8 + rn)*3 + flab(ww*8 + cn);
            float vals[4];
            float vmax = -1e30f;
            #pragma unroll
            for (int j = 0; j < 4; ++j) {
                int m = j*16 + lrow;
                int idx = ((rn - (m >> 3) + 7)*15 + (cn - (m & 7) + 7))*6 + h;
                float val = s[i][j][rg] + rpb_s[idx];
                if (labn != labm[j]) val -= 100.f;
                vals[j] = val;
                vmax = fmaxf(vmax, val);
            }
            #pragma unroll
            for (int o = 1; o < 16; o <<= 1) vmax = fmaxf(vmax, __shfl_xor(vmax, o));
            float sum = 0.f;
            #pragma unroll
            for (int j = 0; j < 4; ++j) { vals[j] = __expf(vals[j] - vmax); sum += vals[j]; }
            #pragma unroll
            for (int o = 1; o < 16; o <<= 1) sum += __shfl_xor(sum, o);
            float inv = 1.f / sum;
            #pragma unroll
            for (int j = 0; j < 4; ++j) pl[n*72 + j*16 + lrow] = f2bf(vals[j]*inv);
        }
    }
    __syncthreads();

    f32x4 oacc[4][2];
    #pragma unroll
    for (int i = 0; i < 4; ++i) { oacc[i][0] = zz; oacc[i][1] = zz; }
    #pragma unroll
    for (int kc = 0; kc < 2; ++kc) {
        s16x8 vf[2];
        #pragma unroll
        for (int jd = 0; jd < 2; ++jd)
            vf[jd] = *(const s16x8*)(vb + (jd*16+lrow)*64 + kc*32 + quad*8);
        #pragma unroll
        for (int i = 0; i < 4; ++i) {
            s16x8 pf = *(const s16x8*)(pl + (i*16+lrow)*72 + kc*32 + quad*8);
            #pragma unroll
            for (int jd = 0; jd < 2; ++jd)
                oacc[i][jd] = __builtin_amdgcn_mfma_f32_16x16x32_bf16(pf, vf[jd], oacc[i][jd], 0, 0, 0);
        }
    }
    unsigned short* ob = ao + (size_t)b_*12288 + h*32;
    #pragma unroll
    for (int i = 0; i < 4; ++i)
        #pragma unroll
        for (int jd = 0; jd < 2; ++jd)
            #pragma unroll
            for (int rg = 0; rg < 4; ++rg) {
                int n = i*16 + quad*4 + rg;
                ob[(size_t)n*192 + jd*16 + lrow] = f2bf(oacc[i][jd][rg]);
            }
}

// =====================================================================
// proj GEMM (full O=192) + window-reverse/roll + residual + LN2, fused.
// One block per window (M=64). Wave owns 16 rows x 192 cols -> row stats
// computable in-wave. Writes x1 fp32 + xln2 bf16 (via LDS, int4 bursts).
// =====================================================================
__global__ __launch_bounds__(256) void projln_kernel(
    const unsigned short* __restrict__ A, const unsigned short* __restrict__ W,
    const float* __restrict__ pbias, const float* __restrict__ x,
    const float* __restrict__ g2, const float* __restrict__ b2,
    float* __restrict__ x1, unsigned short* __restrict__ xln2)
{
    __shared__ __attribute__((aligned(16))) char smem[36864];
    unsigned short* As = (unsigned short*)smem;             // 64x72  (9.2KB)
    unsigned short* Bs = (unsigned short*)(smem + 9216);    // 192x72 (27.6KB)
    const int b_ = blockIdx.x;
    const int tid = threadIdx.x, wv = tid>>6, lane = tid&63;
    const int lrow = lane&15, quad = lane>>4;
    const size_t m0 = (size_t)b_*64;

    f32x4 acc[12];
    #pragma unroll
    for (int j=0;j<12;++j) acc[j] = (f32x4){0.f,0.f,0.f,0.f};

    for (int k0=0;k0<192;k0+=64) {
        __syncthreads();
        #pragma unroll
        for (int t=0;t<2;++t) {
            int cid = tid + t*256;
            *(int4*)(As + (cid>>3)*72 + (cid&7)*8) =
                *(const int4*)(A + (m0 + (cid>>3))*192 + k0 + (cid&7)*8);
        }
        #pragma unroll
        for (int t=0;t<6;++t) {
            int cid = tid + t*256;
            *(int4*)(Bs + (cid>>3)*72 + (cid&7)*8) =
                *(const int4*)(W + (size_t)(cid>>3)*192 + k0 + (cid&7)*8);
        }
        __syncthreads();
        #pragma unroll
        for (int kc=0;kc<2;++kc) {
            s16x8 af = *(const s16x8*)(As + (wv*16+lrow)*72 + kc*32 + quad*8);
            #pragma unroll
            for (int j=0;j<12;++j) {
                s16x8 bf = *(const s16x8*)(Bs + (j*16+lrow)*72 + kc*32 + quad*8);
                acc[j] = __builtin_amdgcn_mfma_f32_16x16x32_bf16(af, bf, acc[j], 0, 0, 0);
            }
        }
    }
    __syncthreads();

    const int bb = b_>>8, wi = b_&255, wh = wi>>4, ww = wi&15;
    float bv[12], gv[12], b2v[12];
    #pragma unroll
    for (int j=0;j<12;++j) {
        bv[j]  = pbias[j*16+lrow];
        gv[j]  = g2[j*16+lrow];
        b2v[j] = b2[j*16+lrow];
    }
    unsigned short* T = (unsigned short*)smem;   // 64x200 (25.6KB <= 36KB)
    #pragma unroll
    for (int rg=0;rg<4;++rg) {
        int n2 = wv*16 + quad*4 + rg;
        int r = n2>>3, c = n2&7;
        int hh = (wh*8+r+4)&127, wp = (ww*8+c+4)&127;   // roll(+4) back
        size_t tok = ((size_t)bb*128+hh)*128 + wp;
        float xv[12];
        float s = 0.f;
        #pragma unroll
        for (int j=0;j<12;++j) {
            float t = acc[j][rg] + bv[j] + x[tok*192 + j*16 + lrow];
            xv[j] = t; s += t;
        }
        #pragma unroll
        for (int o=1;o<16;o<<=1) s += __shfl_xor(s, o);
        float mu = s*(1.0f/192.0f);
        float qv = 0.f;
        #pragma unroll
        for (int j=0;j<12;++j){ float d = xv[j]-mu; qv += d*d; }
        #pragma unroll
        for (int o=1;o<16;o<<=1) qv += __shfl_xor(qv, o);
        float rstd = rsqrtf(qv*(1.0f/192.0f) + 1e-5f);
        #pragma unroll
        for (int j=0;j<12;++j) {
            x1[tok*192 + j*16 + lrow] = xv[j];
            T[n2*200 + j*16 + lrow] = f2bf((xv[j]-mu)*rstd*gv[j] + b2v[j]);
        }
    }
    __syncthreads();
    #pragma unroll
    for (int t=0;t<6;++t) {
        int cid = tid + t*256;                   // 0..1535
        int n2 = cid/24, blk = cid%24;
        int r = n2>>3, c = n2&7;
        int hh = (wh*8+r+4)&127, wp = (ww*8+c+4)&127;
        size_t tok = ((size_t)bb*128+hh)*128 + wp;
        *(int4*)(xln2 + tok*192 + blk*8) = *(const int4*)(T + n2*200 + blk*8);
    }
}

// =====================================================================
// 128x64 GEMM mainloop (async16 + XOR swizzle), 24KB LDS -> ~6 blocks/CU
// wave wv owns rows wv*32..+31 (i in 0..1) x 64 cols (j in 0..3)
// =====================================================================
__device__ __forceinline__ void mm128x64(
    const unsigned short* __restrict__ A, const unsigned short* __restrict__ W,
    int K, size_t m0, int o0, unsigned short* As, unsigned short* Bs,
    f32x4 (&acc)[2][4])
{
    const int tid = threadIdx.x, wv = tid>>6, lane = tid&63;
    const int lrow = lane&15, quad = lane>>4;
    const int lr8 = lane>>3, lb = lane&7;
    const int sb = ((lb ^ lr8) << 3);
    #pragma unroll
    for (int i=0;i<2;++i)
        #pragma unroll
        for (int j=0;j<4;++j) acc[i][j] = (f32x4){0.f,0.f,0.f,0.f};

    const unsigned short* Abase = A + (m0 + wv*8 + lr8)*K + sb;
    const unsigned short* Wbase = W + (size_t)(o0 + wv*8 + lr8)*K + sb;

    for (int k0=0;k0<K;k0+=64) {
        #pragma unroll
        for (int it=0;it<4;++it)
            async16(Abase + (size_t)(it*32)*K + k0, As + (it*4+wv)*512);
        #pragma unroll
        for (int it=0;it<2;++it)
            async16(Wbase + (size_t)(it*32)*K + k0, Bs + (it*4+wv)*512);
        __syncthreads();
        #pragma unroll
        for (int kc=0;kc<2;++kc) {
            const int blk = quad + 4*kc;
            s16x8 af[2], bf[4];
            #pragma unroll
            for (int i=0;i<2;++i) {
                int row = wv*32 + i*16 + lrow;
                af[i] = *(const s16x8*)(As + row*64 + ((blk ^ (row&7)) << 3));
            }
            #pragma unroll
            for (int j=0;j<4;++j) {
                int row = j*16 + lrow;
                bf[j] = *(const s16x8*)(Bs + row*64 + ((blk ^ (row&7)) << 3));
            }
            #pragma unroll
            for (int i=0;i<2;++i)
                #pragma unroll
                for (int j=0;j<4;++j)
                    acc[i][j] = __builtin_amdgcn_mfma_f32_16x16x32_bf16(af[i], bf[j], acc[i][j], 0, 0, 0);
        }
        __syncthreads();
    }
}

// ---------------- FC1 + bias + exact GELU -> h1 bf16 ----------------
__global__ __launch_bounds__(256) void gemm_fc1_kernel(
    const unsigned short* __restrict__ A, const unsigned short* __restrict__ Wm,
    const float* __restrict__ bias, unsigned short* __restrict__ h1)
{
    __shared__ __attribute__((aligned(16))) char smem[24576];
    unsigned short* As = (unsigned short*)smem;            // 128x64 (16KB)
    unsigned short* Bs = (unsigned short*)(smem + 16384);  // 64x64  (8KB)
    const size_t m0 = (size_t)blockIdx.y*128;
    const int o0 = blockIdx.x*64;
    f32x4 acc[2][4];
    mm128x64(A, Wm, 192, m0, o0, As, Bs, acc);
    const int tid = threadIdx.x, wv = tid>>6, lane = tid&63;
    const int lrow = lane&15, quad = lane>>4;
    float bv[4];
    #pragma unroll
    for (int j=0;j<4;++j) bv[j] = bias[o0 + j*16 + lrow];
    unsigned short* T = (unsigned short*)smem;             // 128x72 (18.4KB)
    #pragma unroll
    for (int i=0;i<2;++i)
        #pragma unroll
        for (int j=0;j<4;++j)
            #pragma unroll
            for (int rg=0;rg<4;++rg) {
                int ml = wv*32 + i*16 + quad*4 + rg;
                float v = acc[i][j][rg] + bv[j];
                v = 0.5f*v*(1.0f + erff(v*0.7071067811865475f));
                T[ml*72 + j*16 + lrow] = f2bf(v);
            }
    __syncthreads();
    #pragma unroll
    for (int t=0;t<4;++t) {
        int c = tid + t*256;
        int row = c>>3, blk = c&7;
        *(int4*)(h1 + (m0+row)*768 + o0 + blk*8) = *(const int4*)(T + row*72 + blk*8);
    }
}

// ---------------- FC2 (K=768) + bias + residual -> out fp32 ----------------
__global__ __launch_bounds__(256) void gemm_fc2_kernel(
    const unsigned short* __restrict__ A, const unsigned short* __restrict__ Wm,
    const float* __restrict__ bias, const float* __restrict__ x1, float* __restrict__ out)
{
    __shared__ __attribute__((aligned(16))) char smem[24576];
    unsigned short* As = (unsigned short*)smem;
    unsigned short* Bs = (unsigned short*)(smem + 16384);
    const size_t m0 = (size_t)blockIdx.y*128;
    const int o0 = blockIdx.x*64;
    f32x4 acc[2][4];
    mm128x64(A, Wm, 768, m0, o0, As, Bs, acc);
    const int tid = threadIdx.x, wv = tid>>6, lane = tid&63;
    const int lrow = lane&15, quad = lane>>4;
    float bv[4];
    #pragma unroll
    for (int j=0;j<4;++j) bv[j] = bias[o0 + j*16 + lrow];
    float* T = (float*)smem;                               // 64x68 fp32 (17.4KB)
    #pragma unroll
    for (int p=0;p<2;++p) {
        __syncthreads();
        if ((wv>>1) == p) {
            int wl = wv&1;
            #pragma unroll
            for (int i=0;i<2;++i)
                #pragma unroll
                for (int j=0;j<4;++j)
                    #pragma unroll
                    for (int rg=0;rg<4;++rg)
                        T[(wl*32 + i*16 + quad*4 + rg)*68 + j*16 + lrow] = acc[i][j][rg] + bv[j];
        }
        __syncthreads();
        #pragma unroll
        for (int t=0;t<4;++t) {
            int c = tid + t*256;
            int row = c>>4, blk = c&15;
            size_t ad = (m0 + p*64 + row)*192 + o0 + blk*4;
            float4 v = *(const float4*)(T + row*68 + blk*4);
            float4 rx = *(const float4*)(x1 + ad);
            v.x += rx.x; v.y += rx.y; v.z += rx.z; v.w += rx.w;
            *(float4*)(out + ad) = v;
        }
    }
}

extern "C" void kernel_launch(void* const* d_in, const int* in_sizes, int n_in,
                              void* d_out, int out_size, void* d_ws, size_t ws_size,
                              hipStream_t stream)
{
    const float* x      = (const float*)d_in[0];
    const float* g1     = (const float*)d_in[1];
    const float* b1     = (const float*)d_in[2];
    const float* qkv_w  = (const float*)d_in[3];
    const float* qkv_b  = (const float*)d_in[4];
    const float* rpb    = (const float*)d_in[5];
    const float* proj_w = (const float*)d_in[6];
    const float* proj_b = (const float*)d_in[7];
    const float* g2     = (const float*)d_in[8];
    const float* b2     = (const float*)d_in[9];
    const float* fc1_w  = (const float*)d_in[10];
    const float* fc1_b  = (const float*)d_in[11];
    const float* fc2_w  = (const float*)d_in[12];
    const float* fc2_b  = (const float*)d_in[13];
    float* out = (float*)d_out;
    char* ws = (char*)d_ws;

    if (ws_size < 353206272ULL) return;

    unsigned short* qbuf  = (unsigned short*)(ws + 0);          // 50.3MB
    unsigned short* kbuf  = (unsigned short*)(ws + 50331648);   // 50.3MB
    unsigned short* vbuf  = (unsigned short*)(ws + 100663296);  // 50.3MB (vT)
    unsigned short* attnO = (unsigned short*)(ws + 150994944);  // 50.3MB
    float*          x1    = (float*)        (ws + 201326592);   // 100.7MB
    unsigned short* xln2  = (unsigned short*)(ws + 301989888);  // 50.3MB
    unsigned short* wq    = (unsigned short*)(ws + 352321536);
    unsigned short* wp    = (unsigned short*)(ws + 352321536 + 221184);
    unsigned short* w1    = (unsigned short*)(ws + 352321536 + 221184 + 73728);
    unsigned short* w2    = (unsigned short*)(ws + 352321536 + 221184 + 73728 + 294912);
    unsigned short* h1    = (unsigned short*)(ws + 0);          // 201.3MB overlays q,k,v,attnO

    wconv_all<<<576, 256, 0, stream>>>(qkv_w, proj_w, fc1_w, fc2_w, wq, wp, w1, w2);
    lnqkv_kernel<<<2048, 256, 0, stream>>>(x, g1, b1, wq, qkv_b, qbuf, kbuf, vbuf);
    attn_kernel<<<2048, 384, 0, stream>>>(qbuf, kbuf, vbuf, rpb, attnO);
    projln_kernel<<<2048, 256, 0, stream>>>(attnO, wp, proj_b, x, g2, b2, x1, xln2);
    gemm_fc1_kernel<<<dim3(12, 1024), 256, 0, stream>>>(xln2, w1, fc1_b, h1);
    gemm_fc2_kernel<<<dim3(3, 1024), 256, 0, stream>>>(h1, w2, fc2_b, x1, out);
}